// Round 2
// baseline (153.167 us; speedup 1.0000x reference)
//
#include <hip/hip_runtime.h>
#include <math.h>

#define Bn 256
#define Nn 1024
#define Dn 128
#define Hn 8
#define HDn 16
#define NEG_INF -1.0e15f

// ---------------- K0: Q = h_c @ Wq.T + bq ----------------
__global__ __launch_bounds__(128) void k_q(
    const float* __restrict__ h_g, const float* __restrict__ first,
    const float* __restrict__ last, const float* __restrict__ context,
    const float* __restrict__ Wq, const float* __restrict__ bq,
    float* __restrict__ Qout)
{
    __shared__ __align__(16) float hc[3 * Dn + 2];
    const int b = blockIdx.x;
    const int t = threadIdx.x;
    hc[t]          = h_g[b * Dn + t];
    hc[Dn + t]     = first[b * Dn + t];
    hc[2 * Dn + t] = last[b * Dn + t];
    if (t < 2) hc[3 * Dn + t] = context[b * 2 + t];
    __syncthreads();

    const float2* w2 = (const float2*)(Wq + (size_t)t * (3 * Dn + 2));
    const float2* h2 = (const float2*)hc;
    float acc = bq[t];
#pragma unroll 8
    for (int k = 0; k < (3 * Dn + 2) / 2; ++k) {
        float2 w = w2[k], h = h2[k];
        acc = fmaf(w.x, h.x, fmaf(w.y, h.y, acc));
    }
    Qout[b * Dn + t] = acc;
}

// ---------------- K1: per-(b,h) attention, single fused memory phase ----------------
// 4 lanes per key row n: lane loads one contiguous float4 of K (coalesced 16B/lane)
// and the matching float4 of V (kept in registers). Scores stay in registers.
__global__ __launch_bounds__(256, 4) void k_attn(
    const float* __restrict__ Q, const float* __restrict__ K,
    const float* __restrict__ V, const int* __restrict__ mask,
    float* __restrict__ Uout)
{
    __shared__ float sQ[HDn];
    __shared__ float sRed[4];
    __shared__ float sSum[4];
    __shared__ float sUp[4][HDn];

    const int bh = blockIdx.x;
    const int b = bh >> 3;
    const int tid = threadIdx.x;
    const int lane = tid & 63, wave = tid >> 6;
    const int d4 = tid & 3;      // which float4 of the 16-dim head
    const int g = tid >> 2;      // key-row group 0..63 (16 per wave)

    if (tid < HDn) sQ[tid] = Q[b * Dn + (bh & 7) * HDn + tid];
    __syncthreads();
    const float4 qf = ((const float4*)sQ)[d4];

    const float4* __restrict__ Kp = (const float4*)(K + (size_t)bh * Nn * HDn);
    const float4* __restrict__ Vp = (const float4*)(V + (size_t)bh * Nn * HDn);
    const int* __restrict__ mrow = mask + b * Nn;

    float s[16];
    float4 v[16];
    float lmax = NEG_INF;
#pragma unroll
    for (int i = 0; i < 16; ++i) {
        const int n = g + 64 * i;
        const float4 kf = Kp[(size_t)n * 4 + d4];
        v[i] = Vp[(size_t)n * 4 + d4];
        float p = qf.x * kf.x + qf.y * kf.y + qf.z * kf.z + qf.w * kf.w;
        p += __shfl_xor(p, 1, 64);
        p += __shfl_xor(p, 2, 64);          // all 4 lanes now hold full dot
        p = (mrow[n] == 0) ? NEG_INF : (p * 0.25f);   // /sqrt(16)
        s[i] = p;
        lmax = fmaxf(lmax, p);
    }
    // max across the 16 groups of this wave (bits 2..5), then across waves
#pragma unroll
    for (int o = 4; o <= 32; o <<= 1) lmax = fmaxf(lmax, __shfl_xor(lmax, o, 64));
    if (lane == 0) sRed[wave] = lmax;
    __syncthreads();
    const float m = fmaxf(fmaxf(sRed[0], sRed[1]), fmaxf(sRed[2], sRed[3]));

    float lsum = 0.f;
    float4 acc = {0.f, 0.f, 0.f, 0.f};
#pragma unroll
    for (int i = 0; i < 16; ++i) {
        const float e = __expf(s[i] - m);
        lsum += e;
        acc.x = fmaf(e, v[i].x, acc.x);
        acc.y = fmaf(e, v[i].y, acc.y);
        acc.z = fmaf(e, v[i].z, acc.z);
        acc.w = fmaf(e, v[i].w, acc.w);
    }
    // reduce across the 16 groups (bits 2..5); lanes 0..3 end with dims d4
#pragma unroll
    for (int o = 4; o <= 32; o <<= 1) {
        acc.x += __shfl_xor(acc.x, o, 64);
        acc.y += __shfl_xor(acc.y, o, 64);
        acc.z += __shfl_xor(acc.z, o, 64);
        acc.w += __shfl_xor(acc.w, o, 64);
        lsum  += __shfl_xor(lsum, o, 64);
    }
    if (lane < 4) {
        sUp[wave][lane * 4 + 0] = acc.x;
        sUp[wave][lane * 4 + 1] = acc.y;
        sUp[wave][lane * 4 + 2] = acc.z;
        sUp[wave][lane * 4 + 3] = acc.w;
    }
    if (lane == 0) sSum[wave] = lsum;
    __syncthreads();
    if (tid < HDn) {
        const float inv = 1.0f / (sSum[0] + sSum[1] + sSum[2] + sSum[3]);
        const float u = (sUp[0][tid] + sUp[1][tid] + sUp[2][tid] + sUp[3][tid]) * inv;
        Uout[b * Dn + (bh & 7) * HDn + tid] = u;
    }
}

// ---------------- K2: u2 = u@Wo.T + bo; pointer logits; softmax; argmax ----------------
__global__ __launch_bounds__(512) void k_ptr(
    const float* __restrict__ U, const float* __restrict__ Wo,
    const float* __restrict__ bo, const float* __restrict__ K_lg,
    const int* __restrict__ mask, float* __restrict__ out)
{
    __shared__ __align__(16) float sU[Dn];
    __shared__ __align__(16) float sU2[Dn];
    __shared__ __align__(16) float sL[Nn];
    __shared__ float sRv[8];
    __shared__ int   sRi[8];
    __shared__ float sRs[8];

    const int b = blockIdx.x;
    const int tid = threadIdx.x;
    const int lane = tid & 63, wave = tid >> 6;

    if (tid < Dn) sU[tid] = U[b * Dn + tid];
    __syncthreads();
    // u2: 4 threads per output dim (512 thr / 128 dims)
    {
        const int d = tid >> 2, quarter = tid & 3;
        const float4* wrow = (const float4*)(Wo + (size_t)d * Dn + quarter * 32);
        const float4* su4 = (const float4*)(sU + quarter * 32);
        float acc = 0.f;
#pragma unroll
        for (int k = 0; k < 8; ++k) {
            const float4 w = wrow[k], u = su4[k];
            acc = fmaf(w.x, u.x, fmaf(w.y, u.y, fmaf(w.z, u.z, fmaf(w.w, u.w, acc))));
        }
        acc += __shfl_xor(acc, 1, 64);
        acc += __shfl_xor(acc, 2, 64);
        if (quarter == 0) sU2[d] = acc + bo[d];
    }
    __syncthreads();

    // logits: 16 groups of 32 lanes; u2 fragment hoisted to registers
    const float4* __restrict__ Kl = (const float4*)(K_lg + (size_t)b * Nn * Dn);
    const int* __restrict__ mrow = mask + b * Nn;
    const int grp = tid >> 5, l32 = tid & 31;
    const float4 u2f = ((const float4*)sU2)[l32];
    const float sc = 0.08838834764831845f;   // 1/sqrt(128)
#pragma unroll
    for (int it = 0; it < Nn / 16; ++it) {
        const int n = it * 16 + grp;
        const float4 kl = Kl[(size_t)n * 32 + l32];
        float p = kl.x * u2f.x + kl.y * u2f.y + kl.z * u2f.z + kl.w * u2f.w;
#pragma unroll
        for (int o = 16; o >= 1; o >>= 1) p += __shfl_xor(p, o, 64);
        if (l32 == 0) {
            sL[n] = (mrow[n] == 0) ? NEG_INF : 10.0f * tanhf(p * sc);
        }
    }
    __syncthreads();

    // block argmax (first-occurrence tie-break, matching jnp.argmax)
    float bv = NEG_INF; int bi = 0;
#pragma unroll
    for (int i = 0; i < 2; ++i) {
        const int n = tid + i * 512;
        const float v = sL[n];
        if (v > bv || (v == bv && n < bi)) { bv = v; bi = n; }
    }
#pragma unroll
    for (int o = 32; o >= 1; o >>= 1) {
        const float ov = __shfl_xor(bv, o, 64);
        const int oi = __shfl_xor(bi, o, 64);
        if (ov > bv || (ov == bv && oi < bi)) { bv = ov; bi = oi; }
    }
    if (lane == 0) { sRv[wave] = bv; sRi[wave] = bi; }
    __syncthreads();
    bv = sRv[0]; bi = sRi[0];
#pragma unroll
    for (int w = 1; w < 8; ++w) {
        const float ov = sRv[w]; const int oi = sRi[w];
        if (ov > bv || (ov == bv && oi < bi)) { bv = ov; bi = oi; }
    }

    // sum of exp(l - max); prob at argmax = 1/sum
    float lsum = 0.f;
#pragma unroll
    for (int i = 0; i < 2; ++i) lsum += __expf(sL[tid + i * 512] - bv);
#pragma unroll
    for (int o = 32; o >= 1; o >>= 1) lsum += __shfl_xor(lsum, o, 64);
    if (lane == 0) sRs[wave] = lsum;
    __syncthreads();
    if (tid == 0) {
        float tot = 0.f;
#pragma unroll
        for (int w = 0; w < 8; ++w) tot += sRs[w];
        out[b] = (float)bi;            // vertexes (as float32 values)
        out[Bn + b] = 1.0f / tot;      // probs
    }
}

extern "C" void kernel_launch(void* const* d_in, const int* in_sizes, int n_in,
                              void* d_out, int out_size, void* d_ws, size_t ws_size,
                              hipStream_t stream) {
    // inputs: x, h_g, first, last, context, K, V, K_lg, Wq, bq, Wo, bo, mask, t
    const float* h_g     = (const float*)d_in[1];
    const float* first   = (const float*)d_in[2];
    const float* last    = (const float*)d_in[3];
    const float* context = (const float*)d_in[4];
    const float* K       = (const float*)d_in[5];
    const float* V       = (const float*)d_in[6];
    const float* K_lg    = (const float*)d_in[7];
    const float* Wq      = (const float*)d_in[8];
    const float* bq      = (const float*)d_in[9];
    const float* Wo      = (const float*)d_in[10];
    const float* bo      = (const float*)d_in[11];
    const int*   mask    = (const int*)d_in[12];
    float* out = (float*)d_out;

    float* Qws = (float*)d_ws;             // B*D floats
    float* Uws = Qws + Bn * Dn;            // B*D floats

    k_q   <<<Bn,      128, 0, stream>>>(h_g, first, last, context, Wq, bq, Qws);
    k_attn<<<Bn * Hn, 256, 0, stream>>>(Qws, K, V, mask, Uws);
    k_ptr <<<Bn,      512, 0, stream>>>(Uws, Wo, bo, K_lg, mask, out);
}

// Round 3
// 113.195 us; speedup vs baseline: 1.3531x; 1.3531x over previous
//
#include <hip/hip_runtime.h>
#include <math.h>

#define Bn 256
#define Nn 1024
#define Dn 128
#define Hn 8
#define HDn 16
#define NEG_INF -1.0e15f

// ---------------- K0: Q = h_c @ Wq.T + bq ----------------
__global__ __launch_bounds__(128) void k_q(
    const float* __restrict__ h_g, const float* __restrict__ first,
    const float* __restrict__ last, const float* __restrict__ context,
    const float* __restrict__ Wq, const float* __restrict__ bq,
    float* __restrict__ Qout)
{
    __shared__ __align__(16) float hc[3 * Dn + 2];
    const int b = blockIdx.x;
    const int t = threadIdx.x;
    hc[t]          = h_g[b * Dn + t];
    hc[Dn + t]     = first[b * Dn + t];
    hc[2 * Dn + t] = last[b * Dn + t];
    if (t < 2) hc[3 * Dn + t] = context[b * 2 + t];
    __syncthreads();

    const float2* w2 = (const float2*)(Wq + (size_t)t * (3 * Dn + 2));
    const float2* h2 = (const float2*)hc;
    float acc = bq[t];
#pragma unroll 8
    for (int k = 0; k < (3 * Dn + 2) / 2; ++k) {
        float2 w = w2[k], h = h2[k];
        acc = fmaf(w.x, h.x, fmaf(w.y, h.y, acc));
    }
    Qout[b * Dn + t] = acc;
}

// ---------------- K1: per-(b,h) attention, batched-register loads ----------------
// 4 lanes per key row n. Phase A: ALL 32 K/V float4 loads issued into register
// arrays (sched_barrier stops the scheduler from sinking them). Phase B: compute.
__global__ __launch_bounds__(256) void k_attn(
    const float* __restrict__ Q, const float* __restrict__ K,
    const float* __restrict__ V, const int* __restrict__ mask,
    float* __restrict__ Uout)
{
    __shared__ float sQ[HDn];
    __shared__ __align__(16) int sM[Nn];
    __shared__ float sRed[4];
    __shared__ float sSum[4];
    __shared__ float sUp[4][HDn];

    const int bh = blockIdx.x;
    const int b = bh >> 3;
    const int tid = threadIdx.x;
    const int lane = tid & 63, wave = tid >> 6;
    const int d4 = tid & 3;      // which float4 of the 16-dim head
    const int g = tid >> 2;      // key-row group 0..63

    // stage mask coalesced (int4 per thread), and Q
    ((int4*)sM)[tid] = ((const int4*)(mask + (size_t)b * Nn))[tid];
    if (tid < HDn) sQ[tid] = Q[b * Dn + (bh & 7) * HDn + tid];
    __syncthreads();
    const float4 qf = ((const float4*)sQ)[d4];

    const float4* __restrict__ Kp = (const float4*)(K + (size_t)bh * Nn * HDn);
    const float4* __restrict__ Vp = (const float4*)(V + (size_t)bh * Nn * HDn);

    float4 kf[16], vf[16];
#pragma unroll
    for (int i = 0; i < 16; ++i) kf[i] = Kp[(size_t)(g + 64 * i) * 4 + d4];
#pragma unroll
    for (int i = 0; i < 16; ++i) vf[i] = Vp[(size_t)(g + 64 * i) * 4 + d4];
    __builtin_amdgcn_sched_barrier(0);   // loads stay above; 32 in flight

    float s[16];
    float lmax = NEG_INF;
#pragma unroll
    for (int i = 0; i < 16; ++i) {
        float p = qf.x * kf[i].x + qf.y * kf[i].y + qf.z * kf[i].z + qf.w * kf[i].w;
        p += __shfl_xor(p, 1, 64);
        p += __shfl_xor(p, 2, 64);          // all 4 lanes hold full dot
        p = (sM[g + 64 * i] == 0) ? NEG_INF : (p * 0.25f);   // /sqrt(16)
        s[i] = p;
        lmax = fmaxf(lmax, p);
    }
#pragma unroll
    for (int o = 4; o <= 32; o <<= 1) lmax = fmaxf(lmax, __shfl_xor(lmax, o, 64));
    if (lane == 0) sRed[wave] = lmax;
    __syncthreads();
    const float m = fmaxf(fmaxf(sRed[0], sRed[1]), fmaxf(sRed[2], sRed[3]));

    float lsum = 0.f;
    float4 acc = {0.f, 0.f, 0.f, 0.f};
#pragma unroll
    for (int i = 0; i < 16; ++i) {
        const float e = __expf(s[i] - m);
        lsum += e;
        acc.x = fmaf(e, vf[i].x, acc.x);
        acc.y = fmaf(e, vf[i].y, acc.y);
        acc.z = fmaf(e, vf[i].z, acc.z);
        acc.w = fmaf(e, vf[i].w, acc.w);
    }
#pragma unroll
    for (int o = 4; o <= 32; o <<= 1) {
        acc.x += __shfl_xor(acc.x, o, 64);
        acc.y += __shfl_xor(acc.y, o, 64);
        acc.z += __shfl_xor(acc.z, o, 64);
        acc.w += __shfl_xor(acc.w, o, 64);
        lsum  += __shfl_xor(lsum, o, 64);
    }
    if (lane < 4) {
        sUp[wave][lane * 4 + 0] = acc.x;
        sUp[wave][lane * 4 + 1] = acc.y;
        sUp[wave][lane * 4 + 2] = acc.z;
        sUp[wave][lane * 4 + 3] = acc.w;
    }
    if (lane == 0) sSum[wave] = lsum;
    __syncthreads();
    if (tid < HDn) {
        const float inv = 1.0f / (sSum[0] + sSum[1] + sSum[2] + sSum[3]);
        const float u = (sUp[0][tid] + sUp[1][tid] + sUp[2][tid] + sUp[3][tid]) * inv;
        Uout[b * Dn + (bh & 7) * HDn + tid] = u;
    }
}

// ---------------- K2: u2 = u@Wo.T + bo; pointer logits; softmax; argmax ----------------
__global__ __launch_bounds__(1024) void k_ptr(
    const float* __restrict__ U, const float* __restrict__ Wo,
    const float* __restrict__ bo, const float* __restrict__ K_lg,
    const int* __restrict__ mask, float* __restrict__ out)
{
    __shared__ __align__(16) float sU[Dn];
    __shared__ __align__(16) float sU2[Dn];
    __shared__ __align__(16) float sL[Nn];
    __shared__ float sRv[16];
    __shared__ int   sRi[16];
    __shared__ float sRs[16];

    const int b = blockIdx.x;
    const int tid = threadIdx.x;
    const int lane = tid & 63, wave = tid >> 6;

    if (tid < Dn) sU[tid] = U[b * Dn + tid];
    __syncthreads();
    // u2: 8 threads per output dim (1024 thr / 128 dims)
    {
        const int d = tid >> 3, e8 = tid & 7;
        const float4* wrow = (const float4*)(Wo + (size_t)d * Dn + e8 * 16);
        const float4* su4 = (const float4*)(sU + e8 * 16);
        float acc = 0.f;
#pragma unroll
        for (int k = 0; k < 4; ++k) {
            const float4 w = wrow[k], u = su4[k];
            acc = fmaf(w.x, u.x, fmaf(w.y, u.y, fmaf(w.z, u.z, fmaf(w.w, u.w, acc))));
        }
        acc += __shfl_xor(acc, 1, 64);
        acc += __shfl_xor(acc, 2, 64);
        acc += __shfl_xor(acc, 4, 64);
        if (e8 == 0) sU2[d] = acc + bo[d];
    }
    __syncthreads();

    // logits: 32 groups of 32 lanes; 4-deep batched loads
    const float4* __restrict__ Kl = (const float4*)(K_lg + (size_t)b * Nn * Dn);
    const int* __restrict__ mrow = mask + (size_t)b * Nn;
    const int grp = tid >> 5, l32 = tid & 31;
    const float4 u2f = ((const float4*)sU2)[l32];
    const float sc = 0.08838834764831845f;   // 1/sqrt(128)
#pragma unroll
    for (int it0 = 0; it0 < 32; it0 += 4) {
        float4 kl[4];
#pragma unroll
        for (int j = 0; j < 4; ++j)
            kl[j] = Kl[(size_t)(grp + 32 * (it0 + j)) * 32 + l32];
        __builtin_amdgcn_sched_barrier(0);
#pragma unroll
        for (int j = 0; j < 4; ++j) {
            float p = kl[j].x * u2f.x + kl[j].y * u2f.y + kl[j].z * u2f.z + kl[j].w * u2f.w;
#pragma unroll
            for (int o = 16; o >= 1; o >>= 1) p += __shfl_xor(p, o, 64);
            if (l32 == 0) {
                const int n = grp + 32 * (it0 + j);
                sL[n] = (mrow[n] == 0) ? NEG_INF : 10.0f * tanhf(p * sc);
            }
        }
    }
    __syncthreads();

    // block argmax (first-occurrence tie-break) — one key per thread
    float bv = sL[tid]; int bi = tid;
#pragma unroll
    for (int o = 32; o >= 1; o >>= 1) {
        const float ov = __shfl_xor(bv, o, 64);
        const int oi = __shfl_xor(bi, o, 64);
        if (ov > bv || (ov == bv && oi < bi)) { bv = ov; bi = oi; }
    }
    if (lane == 0) { sRv[wave] = bv; sRi[wave] = bi; }
    __syncthreads();
    bv = sRv[0]; bi = sRi[0];
#pragma unroll
    for (int w = 1; w < 16; ++w) {
        const float ov = sRv[w]; const int oi = sRi[w];
        if (ov > bv || (ov == bv && oi < bi)) { bv = ov; bi = oi; }
    }

    // sum of exp(l - max); prob at argmax = 1/sum
    float lsum = __expf(sL[tid] - bv);
#pragma unroll
    for (int o = 32; o >= 1; o >>= 1) lsum += __shfl_xor(lsum, o, 64);
    if (lane == 0) sRs[wave] = lsum;
    __syncthreads();
    if (tid == 0) {
        float tot = 0.f;
#pragma unroll
        for (int w = 0; w < 16; ++w) tot += sRs[w];
        out[b] = (float)bi;            // vertexes (as float32 values)
        out[Bn + b] = 1.0f / tot;      // probs
    }
}

extern "C" void kernel_launch(void* const* d_in, const int* in_sizes, int n_in,
                              void* d_out, int out_size, void* d_ws, size_t ws_size,
                              hipStream_t stream) {
    // inputs: x, h_g, first, last, context, K, V, K_lg, Wq, bq, Wo, bo, mask, t
    const float* h_g     = (const float*)d_in[1];
    const float* first   = (const float*)d_in[2];
    const float* last    = (const float*)d_in[3];
    const float* context = (const float*)d_in[4];
    const float* K       = (const float*)d_in[5];
    const float* V       = (const float*)d_in[6];
    const float* K_lg    = (const float*)d_in[7];
    const float* Wq      = (const float*)d_in[8];
    const float* bq      = (const float*)d_in[9];
    const float* Wo      = (const float*)d_in[10];
    const float* bo      = (const float*)d_in[11];
    const int*   mask    = (const int*)d_in[12];
    float* out = (float*)d_out;

    float* Qws = (float*)d_ws;             // B*D floats
    float* Uws = Qws + Bn * Dn;            // B*D floats

    k_q   <<<Bn,      128, 0, stream>>>(h_g, first, last, context, Wq, bq, Qws);
    k_attn<<<Bn * Hn, 256, 0, stream>>>(Qws, K, V, mask, Uws);
    k_ptr <<<Bn,     1024, 0, stream>>>(Uws, Wo, bo, K_lg, mask, out);
}